// Round 5
// baseline (4306.931 us; speedup 1.0000x reference)
//
#include <hip/hip_runtime.h>
#include <math.h>

#define NN    34
#define NFH   18
#define NFREQ 612
#define CH    256
#define CIN   255
#define NB    64
#define HW    32
#define PI2   6.2831853071795864769f
#define TSTRIDE 36864   // float2 per freq: 36 packed lower tiles * 1024

__device__ __forceinline__ int tIdx(int I, int J){ return ((I*(I+1))>>1) + J; }

// ---------------- forward FFT stage 1: along w (real -> 18 complex) --------
__global__ __launch_bounds__(256) void kF1(const float* __restrict__ x, float2* __restrict__ U){
  __shared__ float tc[NFH][HW], ts[NFH][HW];
  int tid = threadIdx.x;
  for (int i = tid; i < NFH*HW; i += 256){
    int kx = i >> 5, w = i & 31;
    float s, c; sincosf(-PI2*(float)(kx*(w+1))/34.f, &s, &c);
    tc[kx][w] = c; ts[kx][w] = s;
  }
  __syncthreads();
  int c = blockIdx.x;
  int a = (blockIdx.y << 2) + (tid >> 6);
  int b = tid & 63;
  const float4* xr = (const float4*)(x + (((size_t)b*CH + c)*HW + a)*HW);
  float xv[HW];
#pragma unroll
  for (int t = 0; t < 8; t++){
    float4 v = xr[t];
    xv[4*t] = v.x; xv[4*t+1] = v.y; xv[4*t+2] = v.z; xv[4*t+3] = v.w;
  }
#pragma unroll 1
  for (int kx = 0; kx < NFH; kx++){
    float re = 0.f, im = 0.f;
#pragma unroll
    for (int w = 0; w < HW; w++){ re += xv[w]*tc[kx][w]; im += xv[w]*ts[kx][w]; }
    U[(((size_t)a*NFH + kx)*CH + c)*NB + b] = make_float2(re, im);
  }
}

// ---------------- forward FFT stage 2: along a (32 -> 34 complex), scale 1/34
__global__ __launch_bounds__(512) void kF2(const float2* __restrict__ U, float2* __restrict__ X){
  __shared__ float pc[NN][HW], ps[NN][HW];
  int tid = threadIdx.x;
  for (int i = tid; i < NN*HW; i += 512){
    int ky = i >> 5, a = i & 31;
    float s, c; sincosf(-PI2*(float)(ky*(a+1))/34.f, &s, &c);
    pc[ky][a] = c*(1.f/34.f); ps[ky][a] = s*(1.f/34.f);
  }
  __syncthreads();
  int kx = blockIdx.x;
  int c  = (blockIdx.y << 3) + (tid >> 6);
  int b  = tid & 63;
  float2 u[HW];
#pragma unroll
  for (int a = 0; a < HW; a++) u[a] = U[(((size_t)a*NFH + kx)*CH + c)*NB + b];
#pragma unroll 1
  for (int ky = 0; ky < NN; ky++){
    float re = 0.f, im = 0.f;
#pragma unroll
    for (int a = 0; a < HW; a++){
      float cc = pc[ky][a], ss = ps[ky][a];
      re += u[a].x*cc - u[a].y*ss;
      im += u[a].x*ss + u[a].y*cc;
    }
    X[(((size_t)ky*NFH + kx)*CH + c)*NB + b] = make_float2(re, im);
  }
}

// ---------------- transpose weight: wT[k][o*255+i] = w[o][i][k] ------------
__global__ __launch_bounds__(256) void kT0(const float* __restrict__ w, float* __restrict__ wT){
  int idx = blockIdx.x*256 + threadIdx.x;
  if (idx >= 9*CH*CIN) return;
  int k = idx / (CH*CIN);
  int r = idx - k*(CH*CIN);
  wT[idx] = w[(size_t)r*9 + k];
}

// ---------------- C2[kk=k1*9+k2][o][p] = sum_i w[o,i,k1]*w[p,i,k2] ---------
__global__ __launch_bounds__(256) void kC(const float* __restrict__ wT, float* __restrict__ C2){
  int kk = blockIdx.x;
  int k1 = kk / 9, k2 = kk - k1*9;
  int to = (blockIdx.y >> 2) << 6, tp = (blockIdx.y & 3) << 6;
  __shared__ float As[64][33], Bs[64][33];
  int tid = threadIdx.x;
  int ty = tid >> 4, tx = tid & 15;
  float acc[4][4] = {};
  const float* Ab = wT + (size_t)k1*CH*CIN;
  const float* Bb = wT + (size_t)k2*CH*CIN;
  for (int i0 = 0; i0 < CIN; i0 += 32){
    for (int idx = tid; idx < 64*32; idx += 256){
      int r = idx >> 5, j = idx & 31;
      int i = i0 + j;
      As[r][j] = (i < CIN) ? Ab[(size_t)(to + r)*CIN + i] : 0.f;
      Bs[r][j] = (i < CIN) ? Bb[(size_t)(tp + r)*CIN + i] : 0.f;
    }
    __syncthreads();
#pragma unroll
    for (int j = 0; j < 32; j++){
      float av[4], bv[4];
#pragma unroll
      for (int d = 0; d < 4; d++){ av[d] = As[ty*4+d][j]; bv[d] = Bs[tx*4+d][j]; }
#pragma unroll
      for (int da = 0; da < 4; da++)
#pragma unroll
        for (int db = 0; db < 4; db++) acc[da][db] += av[da]*bv[db];
    }
    __syncthreads();
  }
  float* Cb = C2 + (size_t)kk*CH*CH;
#pragma unroll
  for (int da = 0; da < 4; da++)
#pragma unroll
    for (int db = 0; db < 4; db++)
      Cb[(size_t)(to + ty*4 + da)*CH + tp + tx*4 + db] = acc[da][db];
}

// ---------------- M: packed lower tiles only. block=(tile t, row r, fgrp) ---
__global__ __launch_bounds__(64) void kM(const float* __restrict__ C2, float2* __restrict__ M, int cf0, int cF){
  int t = blockIdx.x;
  int I = 0;
  while ((((I+1)*(I+2))>>1) <= t) I++;
  int J = t - ((I*(I+1))>>1);
  int r = blockIdx.y;
  int o = I*32 + r, p0 = J*32;
  int fl = (blockIdx.z << 6) + threadIdx.x;
  bool act = fl < cF;
  int f = act ? (cf0 + fl) : 0;
  int ky = f / NFH, kx = f - ky*NFH;
  float Pc[5], Ps[5], Qc[5], Qs[5];
#pragma unroll
  for (int d = 0; d < 5; d++){
    float s, c;
    sincosf(-PI2*(float)(ky*(d-2))/34.f, &s, &c);
    Pc[d] = c*(1.f/1156.f); Ps[d] = s*(1.f/1156.f);
    sincosf(-PI2*(float)(kx*(d-2))/34.f, &s, &c);
    Qc[d] = c; Qs[d] = s;
  }
  float ax[32] = {}, ay[32] = {};
  const float* Cb = C2 + (size_t)o*CH + p0;
#pragma unroll 1
  for (int k1 = 0; k1 < 9; k1++){
#pragma unroll 1
    for (int k2 = 0; k2 < 9; k2++){
      int da = k1/3 - k2/3 + 2, db = k1%3 - k2%3 + 2;
      float cr = Pc[da]*Qc[db] - Ps[da]*Qs[db];
      float ci = Pc[da]*Qs[db] + Ps[da]*Qc[db];
      const float* crow = Cb + (size_t)(k1*9 + k2)*CH*CH;
#pragma unroll
      for (int j = 0; j < 32; j++){
        float cv = crow[j];
        ax[j] += cv*cr; ay[j] += cv*ci;
      }
    }
  }
  if (act){
    float2* Mr = M + (size_t)fl*TSTRIDE + ((size_t)t << 10) + (r << 5);
#pragma unroll
    for (int j = 0; j < 32; j++) Mr[j] = make_float2(ax[j], ay[j]);
  }
}

// ---------------- eps = 1e-5 * trace(M)/255 ; diag += eps (packed) ---------
__global__ __launch_bounds__(256) void kEps(float2* __restrict__ M, float* __restrict__ eb, int cf0){
  int fi = blockIdx.x;
  int o = threadIdx.x;
  int I = o >> 5, r = o & 31;
  float2* Mf = M + (size_t)fi*TSTRIDE + ((size_t)tIdx(I,I) << 10) + r*32 + r;
  __shared__ float red[256];
  float d = Mf->x;
  red[o] = d;
  __syncthreads();
  for (int s = 128; s > 0; s >>= 1){ if (o < s) red[o] += red[o+s]; __syncthreads(); }
  float eps = red[0] * (1e-5f/255.f);
  Mf->x = d + eps;
  if (o == 0) eb[cf0 + fi] = eps;
}

// ============ right-looking panel factor, rows in registers ================
// Thread i owns panel row i (h=256-32*pb rows, 32 cols in r[32] registers).
// Unscaled-pivot elimination: A[i][j] -= A[i][k]*conj(A[j][k])/A[k][k];
// one barrier per column via double-buffered LDS column broadcast; final
// column rescale by rsqrt(pivot) yields the Cholesky panel.
__global__ __launch_bounds__(256) void kPanel(float2* __restrict__ Mg, int pb){
  __shared__ float2 colbuf[2][32];
  __shared__ float darr[32];
  int fi = blockIdx.x;
  float2* Tf = Mg + (size_t)fi*TSTRIDE;
  const int h = CH - (pb << 5);
  const int i = threadIdx.x;
  const bool act = i < h;
  float2* rowp = Tf + ((size_t)tIdx(pb + (i >> 5), pb) << 10) + ((i & 31) << 5);
  float2 r[32];
  if (act){
#pragma unroll
    for (int t = 0; t < 16; t++){
      float4 v = ((const float4*)rowp)[t];
      r[2*t]   = make_float2(v.x, v.y);
      r[2*t+1] = make_float2(v.z, v.w);
    }
  }
#pragma unroll
  for (int k = 0; k < 32; k++){
    if (act && i >= k && i < 32) colbuf[k & 1][i] = r[k];
    __syncthreads();
    float pinv = __builtin_amdgcn_rcpf(colbuf[k & 1][k].x);
    if (act && i > k){
      float ax = r[k].x * pinv, ay = r[k].y * pinv;
#pragma unroll
      for (int j = k + 1; j < 32; j++){
        float2 l = colbuf[k & 1][j];          // A[j][k]
        r[j].x -= ax*l.x + ay*l.y;            // a/d * conj(l)
        r[j].y -= ay*l.x - ax*l.y;
      }
    }
  }
  if (act && i < 32) darr[i] = r[i].x;        // pivots d_j
  __syncthreads();
  if (act){
#pragma unroll
    for (int j = 0; j < 32; j++){
      float sc = __frsqrt_rn(fmaxf(darr[j], 1e-30f));
      r[j].x *= sc; r[j].y *= sc;
    }
#pragma unroll
    for (int t = 0; t < 16; t++)
      ((float4*)rowp)[t] = make_float4(r[2*t].x, r[2*t].y, r[2*t+1].x, r[2*t+1].y);
  }
}

// ============ right-looking Cholesky: trailing SYRK/GEMM tile update ========
__global__ __launch_bounds__(256) void kSyrk(float2* __restrict__ Mg, int pb){
  __shared__ float2 As[32][33], Bs[32][33];
  int fi = blockIdx.x;
  int p = blockIdx.y;
  int li = 0;
  while ((((li+1)*(li+2)) >> 1) <= p) li++;
  int lj = p - ((li*(li+1)) >> 1);
  int I = pb + 1 + li, J = pb + 1 + lj;
  float2* Tf = Mg + (size_t)fi*TSTRIDE;
  const float2* Asrc = Tf + ((size_t)tIdx(I, pb) << 10);
  const float2* Bsrc = Tf + ((size_t)tIdx(J, pb) << 10);
  float2* Cdst = Tf + ((size_t)tIdx(I, J) << 10);
  int tid = threadIdx.x;
  for (int idx = tid; idx < 1024; idx += 256){
    int r = idx >> 5, c = idx & 31;
    As[r][c] = Asrc[idx];
    Bs[r][c] = Bsrc[idx];
  }
  int r = tid >> 3, c0 = (tid & 7) << 2;
  float2 acc[4];
  float4 c01 = *(const float4*)(Cdst + r*32 + c0);
  float4 c23 = *(const float4*)(Cdst + r*32 + c0 + 2);
  acc[0] = make_float2(c01.x, c01.y); acc[1] = make_float2(c01.z, c01.w);
  acc[2] = make_float2(c23.x, c23.y); acc[3] = make_float2(c23.z, c23.w);
  __syncthreads();
#pragma unroll 4
  for (int k = 0; k < 32; k++){
    float2 a = As[r][k];
#pragma unroll
    for (int d = 0; d < 4; d++){
      float2 b = Bs[c0 + d][k];
      acc[d].x -= a.x*b.x + a.y*b.y;    // a * conj(b)
      acc[d].y -= a.y*b.x - a.x*b.y;
    }
  }
  *(float4*)(Cdst + r*32 + c0)     = make_float4(acc[0].x, acc[0].y, acc[1].x, acc[1].y);
  *(float4*)(Cdst + r*32 + c0 + 2) = make_float4(acc[2].x, acc[2].y, acc[3].x, acc[3].y);
}

// ================= TRSM solve: 8 waves, 32 rows/wave, diag in registers ====
// Wave wv owns rows [32wv,32wv+32), lane c = RHS column. Lt slots wave-private.
template<bool FWD>
__device__ __forceinline__ void solvePhase(int jb, const float2* __restrict__ Tf,
    float2 (&s)[32], float2 (&Lt)[8][32][32], float2 (&S32)[32][64],
    int wv, int c){
  bool need = FWD ? (wv >= jb) : (wv <= jb);
  if (need){
    const float2* src = Tf + ((size_t)(FWD ? tIdx(wv, jb) : tIdx(jb, wv)) << 10);
#pragma unroll
    for (int t = 0; t < 8; t++){
      int idx = t*64 + c, row = idx >> 4, cp = idx & 15;
      float4 v = *(const float4*)(src + row*32 + cp*2);
      *(float4*)(&Lt[wv][row][cp*2]) = v;
    }
  }
  if (wv == jb){
    if (FWD){
#pragma unroll
      for (int k = 0; k < 32; k++){
        float dinv = __builtin_amdgcn_rcpf(Lt[wv][k][k].x);
        float2 v = make_float2(s[k].x*dinv, s[k].y*dinv);
        s[k] = v;
#pragma unroll
        for (int i = k+1; i < 32; i++){
          float2 l = Lt[wv][i][k];
          s[i].x -= l.x*v.x - l.y*v.y;
          s[i].y -= l.x*v.y + l.y*v.x;
        }
      }
    } else {
#pragma unroll
      for (int k = 31; k >= 0; k--){
        float dinv = __builtin_amdgcn_rcpf(Lt[wv][k][k].x);
        float2 v = make_float2(s[k].x*dinv, s[k].y*dinv);
        s[k] = v;
#pragma unroll
        for (int i = 0; i < k; i++){
          float2 l = Lt[wv][k][i];            // conj(L[k][i])
          s[i].x -= l.x*v.x + l.y*v.y;
          s[i].y -= l.x*v.y - l.y*v.x;
        }
      }
    }
#pragma unroll
    for (int i = 0; i < 32; i++) S32[i][c] = s[i];
  }
  __syncthreads();
  bool upd = FWD ? (wv > jb) : (wv < jb);
  if (upd){
#pragma unroll 2
    for (int k = 0; k < 32; k++){
      float2 b = S32[k][c];
      if (FWD){
#pragma unroll
        for (int i = 0; i < 32; i++){
          float2 l = Lt[wv][i][k];
          s[i].x -= l.x*b.x - l.y*b.y;
          s[i].y -= l.x*b.y + l.y*b.x;
        }
      } else {
#pragma unroll
        for (int i = 0; i < 32; i++){
          float2 l = Lt[wv][k][i];            // conj(L[k][i])
          s[i].x -= l.x*b.x + l.y*b.y;
          s[i].y -= l.x*b.y - l.y*b.x;
        }
      }
    }
  }
  __syncthreads();
}

__global__ __launch_bounds__(512, 2) void kSolve(const float2* __restrict__ Lg, float2* __restrict__ X,
                                                 const float* __restrict__ eb, int cf0){
  __shared__ __align__(16) float2 Lt[8][32][32];   // 64 KiB
  __shared__ float2 S32[32][64];                    // 16 KiB
  int fi = blockIdx.x;
  int f = cf0 + fi;
  const float2* Tf = Lg + (size_t)fi*TSTRIDE;
  float2* Xf = X + (size_t)f*CH*NB;
  int tid = threadIdx.x, wv = tid >> 6, c = tid & 63;
  float2 s[32];
#pragma unroll
  for (int i = 0; i < 32; i++) s[i] = Xf[(size_t)(wv*32 + i)*NB + c];
#pragma unroll 1
  for (int jb = 0; jb < 8; jb++)
    solvePhase<true>(jb, Tf, s, Lt, S32, wv, c);
#pragma unroll 1
  for (int jb = 7; jb >= 0; jb--)
    solvePhase<false>(jb, Tf, s, Lt, S32, wv, c);
  float te = 2.f * eb[f];
#pragma unroll
  for (int i = 0; i < 32; i++){
    float2 xv = Xf[(size_t)(wv*32 + i)*NB + c];
    float2 sv = s[i];
    Xf[(size_t)(wv*32 + i)*NB + c] = make_float2(te*sv.x - xv.x, te*sv.y - xv.y);
  }
}

// ---------------- inverse FFT stage 1: along ky (34 -> rows a=1..32) -------
__global__ __launch_bounds__(512) void kI1(const float2* __restrict__ X, float2* __restrict__ Y){
  __shared__ float pc[HW][NN], ps[HW][NN];
  int tid = threadIdx.x;
  for (int i = tid; i < HW*NN; i += 512){
    int a = i / NN, ky = i - a*NN;
    float s, c; sincosf(PI2*(float)(ky*(a+1))/34.f, &s, &c);
    pc[a][ky] = c; ps[a][ky] = s;
  }
  __syncthreads();
  int kx = blockIdx.x;
  int cc = (blockIdx.y << 3) + (tid >> 6);
  int b = tid & 63;
  float2 z[NN];
#pragma unroll
  for (int ky = 0; ky < NN; ky++) z[ky] = X[(((size_t)ky*NFH + kx)*CH + cc)*NB + b];
#pragma unroll 1
  for (int a = 0; a < HW; a++){
    float re = 0.f, im = 0.f;
#pragma unroll
    for (int ky = 0; ky < NN; ky++){
      float co = pc[a][ky], si = ps[a][ky];
      re += z[ky].x*co - z[ky].y*si;
      im += z[ky].x*si + z[ky].y*co;
    }
    Y[(((size_t)a*NFH + kx)*CH + cc)*NB + b] = make_float2(re, im);
  }
}

// ---------------- inverse FFT stage 2: along kx (18 -> real w=1..32) + bias
__global__ __launch_bounds__(256) void kI2(const float2* __restrict__ Y, const float* __restrict__ bias,
                                           float* __restrict__ out){
  __shared__ float tc[NFH][HW], tsn[NFH][HW];
  int tid = threadIdx.x;
  for (int i = tid; i < NFH*HW; i += 256){
    int kx = i >> 5, w = i & 31;
    float wt = (kx == 0 || kx == 17) ? (1.f/34.f) : (2.f/34.f);
    float s, c; sincosf(PI2*(float)(kx*(w+1))/34.f, &s, &c);
    tc[kx][w] = wt*c; tsn[kx][w] = wt*s;
  }
  __syncthreads();
  int cc = blockIdx.x;
  int a = (blockIdx.y << 2) + (tid >> 6);
  int b = tid & 63;
  float2 yv[NFH];
#pragma unroll
  for (int kx = 0; kx < NFH; kx++) yv[kx] = Y[(((size_t)a*NFH + kx)*CH + cc)*NB + b];
  float bi = bias[cc];
  float ov[HW];
#pragma unroll
  for (int w = 0; w < HW; w++){
    float acc = bi;
#pragma unroll
    for (int kx = 0; kx < NFH; kx++)
      acc += yv[kx].x*tc[kx][w] - yv[kx].y*tsn[kx][w];
    ov[w] = acc;
  }
  float4* op = (float4*)(out + (((size_t)b*CH + cc)*HW + a)*HW);
#pragma unroll
  for (int t = 0; t < 8; t++) op[t] = make_float4(ov[4*t], ov[4*t+1], ov[4*t+2], ov[4*t+3]);
}

extern "C" void kernel_launch(void* const* d_in, const int* in_sizes, int n_in,
                              void* d_out, int out_size, void* d_ws, size_t ws_size,
                              hipStream_t stream){
  (void)in_sizes; (void)n_in; (void)out_size;
  const float* x    = (const float*)d_in[0];
  const float* w    = (const float*)d_in[1];
  const float* bias = (const float*)d_in[2];
  float* out = (float*)d_out;
  char* ws = (char*)d_ws;

  const size_t X_BYTES  = (size_t)NFREQ*CH*NB*sizeof(float2);   // 80.2 MB
  const size_t WT_BYTES = (size_t)9*CH*CIN*sizeof(float);       // 2.35 MB
  const size_t C_BYTES  = (size_t)81*CH*CH*sizeof(float);       // 21.2 MB
  const size_t offX  = 0;
  const size_t offWT = offX + X_BYTES;
  const size_t offC  = offWT + WT_BYTES;
  const size_t offE  = offC + C_BYTES;
  const size_t offChunk = offE + 4096;
  const size_t perF = (size_t)TSTRIDE * sizeof(float2);          // 288 KB

  float2* X  = (float2*)(ws + offX);
  float*  wT = (float*)(ws + offWT);
  float*  C2 = (float*)(ws + offC);
  float*  eb = (float*)(ws + offE);
  float2* U  = (float2*)(ws + offChunk);
  float2* Mb = (float2*)(ws + offChunk);
  float2* Y  = (float2*)(ws + offChunk);

  size_t avail = ws_size > offChunk ? ws_size - offChunk : 0;
  int F = (int)(avail / perF);
  if (F < 1) F = 1;
  if (F > NFREQ) F = NFREQ;
  int nch = (NFREQ + F - 1) / F;
  F = (NFREQ + nch - 1) / nch;

  kF1<<<dim3(CH, 8), 256, 0, stream>>>(x, U);
  kF2<<<dim3(NFH, 32), 512, 0, stream>>>(U, X);
  kT0<<<(9*CH*CIN + 255)/256, 256, 0, stream>>>(w, wT);
  kC<<<dim3(81, 16), 256, 0, stream>>>(wT, C2);

  for (int cf0 = 0; cf0 < NFREQ; cf0 += F){
    int cF = (NFREQ - cf0 < F) ? (NFREQ - cf0) : F;
    kM<<<dim3(36, 32, (cF + 63) >> 6), 64, 0, stream>>>(C2, Mb, cf0, cF);
    kEps<<<cF, 256, 0, stream>>>(Mb, eb, cf0);
    for (int pb = 0; pb < 8; pb++){
      kPanel<<<cF, 256, 0, stream>>>(Mb, pb);
      int nrem = 7 - pb;
      int npairs = (nrem*(nrem+1)) >> 1;
      if (npairs > 0)
        kSyrk<<<dim3(cF, npairs), 256, 0, stream>>>(Mb, pb);
    }
    kSolve<<<cF, 512, 0, stream>>>(Mb, X, eb, cf0);
  }

  kI1<<<dim3(NFH, 32), 512, 0, stream>>>(X, Y);
  kI2<<<dim3(CH, 8), 256, 0, stream>>>(Y, bias, out);
}

// Round 6
// 3431.337 us; speedup vs baseline: 1.2552x; 1.2552x over previous
//
#include <hip/hip_runtime.h>
#include <math.h>

#define NN    34
#define NFH   18
#define NFREQ 612
#define CH    256
#define CIN   255
#define NB    64
#define HW    32
#define PI2   6.2831853071795864769f
#define TSTRIDE 36864   // float2 per freq: 36 packed lower tiles * 1024

__device__ __forceinline__ int tIdx(int I, int J){ return ((I*(I+1))>>1) + J; }

// ---------------- forward FFT stage 1: along w (real -> 18 complex) --------
__global__ __launch_bounds__(256) void kF1(const float* __restrict__ x, float2* __restrict__ U){
  __shared__ float tc[NFH][HW], ts[NFH][HW];
  int tid = threadIdx.x;
  for (int i = tid; i < NFH*HW; i += 256){
    int kx = i >> 5, w = i & 31;
    float s, c; sincosf(-PI2*(float)(kx*(w+1))/34.f, &s, &c);
    tc[kx][w] = c; ts[kx][w] = s;
  }
  __syncthreads();
  int c = blockIdx.x;
  int a = (blockIdx.y << 2) + (tid >> 6);
  int b = tid & 63;
  const float4* xr = (const float4*)(x + (((size_t)b*CH + c)*HW + a)*HW);
  float xv[HW];
#pragma unroll
  for (int t = 0; t < 8; t++){
    float4 v = xr[t];
    xv[4*t] = v.x; xv[4*t+1] = v.y; xv[4*t+2] = v.z; xv[4*t+3] = v.w;
  }
#pragma unroll 1
  for (int kx = 0; kx < NFH; kx++){
    float re = 0.f, im = 0.f;
#pragma unroll
    for (int w = 0; w < HW; w++){ re += xv[w]*tc[kx][w]; im += xv[w]*ts[kx][w]; }
    U[(((size_t)a*NFH + kx)*CH + c)*NB + b] = make_float2(re, im);
  }
}

// ---------------- forward FFT stage 2: along a (32 -> 34 complex), scale 1/34
__global__ __launch_bounds__(512) void kF2(const float2* __restrict__ U, float2* __restrict__ X){
  __shared__ float pc[NN][HW], ps[NN][HW];
  int tid = threadIdx.x;
  for (int i = tid; i < NN*HW; i += 512){
    int ky = i >> 5, a = i & 31;
    float s, c; sincosf(-PI2*(float)(ky*(a+1))/34.f, &s, &c);
    pc[ky][a] = c*(1.f/34.f); ps[ky][a] = s*(1.f/34.f);
  }
  __syncthreads();
  int kx = blockIdx.x;
  int c  = (blockIdx.y << 3) + (tid >> 6);
  int b  = tid & 63;
  float2 u[HW];
#pragma unroll
  for (int a = 0; a < HW; a++) u[a] = U[(((size_t)a*NFH + kx)*CH + c)*NB + b];
#pragma unroll 1
  for (int ky = 0; ky < NN; ky++){
    float re = 0.f, im = 0.f;
#pragma unroll
    for (int a = 0; a < HW; a++){
      float cc = pc[ky][a], ss = ps[ky][a];
      re += u[a].x*cc - u[a].y*ss;
      im += u[a].x*ss + u[a].y*cc;
    }
    X[(((size_t)ky*NFH + kx)*CH + c)*NB + b] = make_float2(re, im);
  }
}

// ---------------- transpose weight: wT[k][o*255+i] = w[o][i][k] ------------
__global__ __launch_bounds__(256) void kT0(const float* __restrict__ w, float* __restrict__ wT){
  int idx = blockIdx.x*256 + threadIdx.x;
  if (idx >= 9*CH*CIN) return;
  int k = idx / (CH*CIN);
  int r = idx - k*(CH*CIN);
  wT[idx] = w[(size_t)r*9 + k];
}

// ---------------- C2[kk=k1*9+k2][o][p] = sum_i w[o,i,k1]*w[p,i,k2] ---------
__global__ __launch_bounds__(256) void kC(const float* __restrict__ wT, float* __restrict__ C2){
  int kk = blockIdx.x;
  int k1 = kk / 9, k2 = kk - k1*9;
  int to = (blockIdx.y >> 2) << 6, tp = (blockIdx.y & 3) << 6;
  __shared__ float As[64][33], Bs[64][33];
  int tid = threadIdx.x;
  int ty = tid >> 4, tx = tid & 15;
  float acc[4][4] = {};
  const float* Ab = wT + (size_t)k1*CH*CIN;
  const float* Bb = wT + (size_t)k2*CH*CIN;
  for (int i0 = 0; i0 < CIN; i0 += 32){
    for (int idx = tid; idx < 64*32; idx += 256){
      int r = idx >> 5, j = idx & 31;
      int i = i0 + j;
      As[r][j] = (i < CIN) ? Ab[(size_t)(to + r)*CIN + i] : 0.f;
      Bs[r][j] = (i < CIN) ? Bb[(size_t)(tp + r)*CIN + i] : 0.f;
    }
    __syncthreads();
#pragma unroll
    for (int j = 0; j < 32; j++){
      float av[4], bv[4];
#pragma unroll
      for (int d = 0; d < 4; d++){ av[d] = As[ty*4+d][j]; bv[d] = Bs[tx*4+d][j]; }
#pragma unroll
      for (int da = 0; da < 4; da++)
#pragma unroll
        for (int db = 0; db < 4; db++) acc[da][db] += av[da]*bv[db];
    }
    __syncthreads();
  }
  float* Cb = C2 + (size_t)kk*CH*CH;
#pragma unroll
  for (int da = 0; da < 4; da++)
#pragma unroll
    for (int db = 0; db < 4; db++)
      Cb[(size_t)(to + ty*4 + da)*CH + tp + tx*4 + db] = acc[da][db];
}

// ---------------- M: packed lower tiles only. block=(tile t, row r, fgrp) ---
__global__ __launch_bounds__(64) void kM(const float* __restrict__ C2, float2* __restrict__ M, int cf0, int cF){
  int t = blockIdx.x;
  int I = 0;
  while ((((I+1)*(I+2))>>1) <= t) I++;
  int J = t - ((I*(I+1))>>1);
  int r = blockIdx.y;
  int o = I*32 + r, p0 = J*32;
  int fl = (blockIdx.z << 6) + threadIdx.x;
  bool act = fl < cF;
  int f = act ? (cf0 + fl) : 0;
  int ky = f / NFH, kx = f - ky*NFH;
  float Pc[5], Ps[5], Qc[5], Qs[5];
#pragma unroll
  for (int d = 0; d < 5; d++){
    float s, c;
    sincosf(-PI2*(float)(ky*(d-2))/34.f, &s, &c);
    Pc[d] = c*(1.f/1156.f); Ps[d] = s*(1.f/1156.f);
    sincosf(-PI2*(float)(kx*(d-2))/34.f, &s, &c);
    Qc[d] = c; Qs[d] = s;
  }
  float ax[32] = {}, ay[32] = {};
  const float* Cb = C2 + (size_t)o*CH + p0;
#pragma unroll 1
  for (int k1 = 0; k1 < 9; k1++){
#pragma unroll 1
    for (int k2 = 0; k2 < 9; k2++){
      int da = k1/3 - k2/3 + 2, db = k1%3 - k2%3 + 2;
      float cr = Pc[da]*Qc[db] - Ps[da]*Qs[db];
      float ci = Pc[da]*Qs[db] + Ps[da]*Qc[db];
      const float* crow = Cb + (size_t)(k1*9 + k2)*CH*CH;
#pragma unroll
      for (int j = 0; j < 32; j++){
        float cv = crow[j];
        ax[j] += cv*cr; ay[j] += cv*ci;
      }
    }
  }
  if (act){
    float2* Mr = M + (size_t)fl*TSTRIDE + ((size_t)t << 10) + (r << 5);
#pragma unroll
    for (int j = 0; j < 32; j++) Mr[j] = make_float2(ax[j], ay[j]);
  }
}

// ---------------- eps = 1e-5 * trace(M)/255 ; diag += eps (packed) ---------
__global__ __launch_bounds__(256) void kEps(float2* __restrict__ M, float* __restrict__ eb, int cf0){
  int fi = blockIdx.x;
  int o = threadIdx.x;
  int I = o >> 5, r = o & 31;
  float2* Mf = M + (size_t)fi*TSTRIDE + ((size_t)tIdx(I,I) << 10) + r*32 + r;
  __shared__ float red[256];
  float d = Mf->x;
  red[o] = d;
  __syncthreads();
  for (int s = 128; s > 0; s >>= 1){ if (o < s) red[o] += red[o+s]; __syncthreads(); }
  float eps = red[0] * (1e-5f/255.f);
  Mf->x = d + eps;
  if (o == 0) eb[cf0 + fi] = eps;
}

// ============ right-looking panel factor, rows in registers ================
__global__ __launch_bounds__(256) void kPanel(float2* __restrict__ Mg, int pb){
  __shared__ float2 colbuf[2][32];
  __shared__ float darr[32];
  int fi = blockIdx.x;
  float2* Tf = Mg + (size_t)fi*TSTRIDE;
  const int h = CH - (pb << 5);
  const int i = threadIdx.x;
  const bool act = i < h;
  float2* rowp = Tf + ((size_t)tIdx(pb + (i >> 5), pb) << 10) + ((i & 31) << 5);
  float2 r[32];
  if (act){
#pragma unroll
    for (int t = 0; t < 16; t++){
      float4 v = ((const float4*)rowp)[t];
      r[2*t]   = make_float2(v.x, v.y);
      r[2*t+1] = make_float2(v.z, v.w);
    }
  }
#pragma unroll
  for (int k = 0; k < 32; k++){
    if (act && i >= k && i < 32) colbuf[k & 1][i] = r[k];
    __syncthreads();
    float pinv = __builtin_amdgcn_rcpf(colbuf[k & 1][k].x);
    if (act && i > k){
      float ax = r[k].x * pinv, ay = r[k].y * pinv;
#pragma unroll
      for (int j = k + 1; j < 32; j++){
        float2 l = colbuf[k & 1][j];
        r[j].x -= ax*l.x + ay*l.y;
        r[j].y -= ay*l.x - ax*l.y;
      }
    }
  }
  if (act && i < 32) darr[i] = r[i].x;
  __syncthreads();
  if (act){
#pragma unroll
    for (int j = 0; j < 32; j++){
      float sc = __frsqrt_rn(fmaxf(darr[j], 1e-30f));
      r[j].x *= sc; r[j].y *= sc;
    }
#pragma unroll
    for (int t = 0; t < 16; t++)
      ((float4*)rowp)[t] = make_float4(r[2*t].x, r[2*t].y, r[2*t+1].x, r[2*t+1].y);
  }
}

// ============ right-looking Cholesky: trailing SYRK/GEMM tile update ========
__global__ __launch_bounds__(256) void kSyrk(float2* __restrict__ Mg, int pb){
  __shared__ float2 As[32][33], Bs[32][33];
  int fi = blockIdx.x;
  int p = blockIdx.y;
  int li = 0;
  while ((((li+1)*(li+2)) >> 1) <= p) li++;
  int lj = p - ((li*(li+1)) >> 1);
  int I = pb + 1 + li, J = pb + 1 + lj;
  float2* Tf = Mg + (size_t)fi*TSTRIDE;
  const float2* Asrc = Tf + ((size_t)tIdx(I, pb) << 10);
  const float2* Bsrc = Tf + ((size_t)tIdx(J, pb) << 10);
  float2* Cdst = Tf + ((size_t)tIdx(I, J) << 10);
  int tid = threadIdx.x;
  for (int idx = tid; idx < 1024; idx += 256){
    int r = idx >> 5, c = idx & 31;
    As[r][c] = Asrc[idx];
    Bs[r][c] = Bsrc[idx];
  }
  int r = tid >> 3, c0 = (tid & 7) << 2;
  float2 acc[4];
  float4 c01 = *(const float4*)(Cdst + r*32 + c0);
  float4 c23 = *(const float4*)(Cdst + r*32 + c0 + 2);
  acc[0] = make_float2(c01.x, c01.y); acc[1] = make_float2(c01.z, c01.w);
  acc[2] = make_float2(c23.x, c23.y); acc[3] = make_float2(c23.z, c23.w);
  __syncthreads();
#pragma unroll 4
  for (int k = 0; k < 32; k++){
    float2 a = As[r][k];
#pragma unroll
    for (int d = 0; d < 4; d++){
      float2 b = Bs[c0 + d][k];
      acc[d].x -= a.x*b.x + a.y*b.y;
      acc[d].y -= a.y*b.x - a.x*b.y;
    }
  }
  *(float4*)(Cdst + r*32 + c0)     = make_float4(acc[0].x, acc[0].y, acc[1].x, acc[1].y);
  *(float4*)(Cdst + r*32 + c0 + 2) = make_float4(acc[2].x, acc[2].y, acc[3].x, acc[3].y);
}

// ================= wave-independent TRSM solve =============================
// 4 blocks/freq (blockIdx.y = col-quarter), 128 thr = 2 waves; each wave
// independently solves 8 RHS cols. lane: hf=lane>>5 (col-quad), r=lane&31=row.
// S: s[8][4] complex in VGPRs (compile-time indexed via templates). Tiles
// stream through double-buffered padded LDS; diag solved per-wave via shfl.

template<int RB>
__device__ __forceinline__ void updF(float2 (&s)[8][4], const float2* __restrict__ tb,
                                     const float2* __restrict__ vb, int r, int hf){
#pragma unroll 2
  for (int k = 0; k < 32; k++){
    float2 l = tb[r*33 + k];
    const float2* vp = vb + k*10 + (hf<<2);
    float2 v0 = vp[0], v1 = vp[1], v2 = vp[2], v3 = vp[3];
    s[RB][0].x -= l.x*v0.x - l.y*v0.y; s[RB][0].y -= l.x*v0.y + l.y*v0.x;
    s[RB][1].x -= l.x*v1.x - l.y*v1.y; s[RB][1].y -= l.x*v1.y + l.y*v1.x;
    s[RB][2].x -= l.x*v2.x - l.y*v2.y; s[RB][2].y -= l.x*v2.y + l.y*v2.x;
    s[RB][3].x -= l.x*v3.x - l.y*v3.y; s[RB][3].y -= l.x*v3.y + l.y*v3.x;
  }
}

template<int RB>
__device__ __forceinline__ void updB(float2 (&s)[8][4], const float2* __restrict__ tb,
                                     const float2* __restrict__ vb, int r, int hf){
#pragma unroll 2
  for (int k = 0; k < 32; k++){
    float2 l = tb[k*33 + r];
    const float2* vp = vb + k*10 + (hf<<2);
    float2 v0 = vp[0], v1 = vp[1], v2 = vp[2], v3 = vp[3];
    s[RB][0].x -= l.x*v0.x + l.y*v0.y; s[RB][0].y -= l.x*v0.y - l.y*v0.x;
    s[RB][1].x -= l.x*v1.x + l.y*v1.y; s[RB][1].y -= l.x*v1.y - l.y*v1.x;
    s[RB][2].x -= l.x*v2.x + l.y*v2.y; s[RB][2].y -= l.x*v2.y - l.y*v2.x;
    s[RB][3].x -= l.x*v3.x + l.y*v3.y; s[RB][3].y -= l.x*v3.y - l.y*v3.x;
  }
}

template<int JB>
__device__ __forceinline__ void diagF(float2 (&s)[8][4], const float2* __restrict__ tb,
                                      float2* __restrict__ vb, int r, int hf){
  float2 sv0 = s[JB][0], sv1 = s[JB][1], sv2 = s[JB][2], sv3 = s[JB][3];
  int src = hf << 5;
#pragma unroll 1
  for (int k = 0; k < 32; k++){
    float dinv = __builtin_amdgcn_rcpf(tb[k*33 + k].x);
    float c0x = sv0.x*dinv, c0y = sv0.y*dinv;
    float c1x = sv1.x*dinv, c1y = sv1.y*dinv;
    float c2x = sv2.x*dinv, c2y = sv2.y*dinv;
    float c3x = sv3.x*dinv, c3y = sv3.y*dinv;
    float2 v0, v1, v2, v3;
    v0.x = __shfl(c0x, src + k, 64); v0.y = __shfl(c0y, src + k, 64);
    v1.x = __shfl(c1x, src + k, 64); v1.y = __shfl(c1y, src + k, 64);
    v2.x = __shfl(c2x, src + k, 64); v2.y = __shfl(c2y, src + k, 64);
    v3.x = __shfl(c3x, src + k, 64); v3.y = __shfl(c3y, src + k, 64);
    if (r == k){ sv0 = v0; sv1 = v1; sv2 = v2; sv3 = v3; }
    else if (r > k){
      float2 l = tb[r*33 + k];
      sv0.x -= l.x*v0.x - l.y*v0.y; sv0.y -= l.x*v0.y + l.y*v0.x;
      sv1.x -= l.x*v1.x - l.y*v1.y; sv1.y -= l.x*v1.y + l.y*v1.x;
      sv2.x -= l.x*v2.x - l.y*v2.y; sv2.y -= l.x*v2.y + l.y*v2.x;
      sv3.x -= l.x*v3.x - l.y*v3.y; sv3.y -= l.x*v3.y + l.y*v3.x;
    }
  }
  s[JB][0] = sv0; s[JB][1] = sv1; s[JB][2] = sv2; s[JB][3] = sv3;
  float2* wp = vb + r*10 + (hf<<2);
  wp[0] = sv0; wp[1] = sv1; wp[2] = sv2; wp[3] = sv3;
}

template<int JB>
__device__ __forceinline__ void diagB(float2 (&s)[8][4], const float2* __restrict__ tb,
                                      float2* __restrict__ vb, int r, int hf){
  float2 sv0 = s[JB][0], sv1 = s[JB][1], sv2 = s[JB][2], sv3 = s[JB][3];
  int src = hf << 5;
#pragma unroll 1
  for (int k = 31; k >= 0; k--){
    float dinv = __builtin_amdgcn_rcpf(tb[k*33 + k].x);
    float c0x = sv0.x*dinv, c0y = sv0.y*dinv;
    float c1x = sv1.x*dinv, c1y = sv1.y*dinv;
    float c2x = sv2.x*dinv, c2y = sv2.y*dinv;
    float c3x = sv3.x*dinv, c3y = sv3.y*dinv;
    float2 v0, v1, v2, v3;
    v0.x = __shfl(c0x, src + k, 64); v0.y = __shfl(c0y, src + k, 64);
    v1.x = __shfl(c1x, src + k, 64); v1.y = __shfl(c1y, src + k, 64);
    v2.x = __shfl(c2x, src + k, 64); v2.y = __shfl(c2y, src + k, 64);
    v3.x = __shfl(c3x, src + k, 64); v3.y = __shfl(c3y, src + k, 64);
    if (r == k){ sv0 = v0; sv1 = v1; sv2 = v2; sv3 = v3; }
    else if (r < k){
      float2 l = tb[k*33 + r];
      sv0.x -= l.x*v0.x + l.y*v0.y; sv0.y -= l.x*v0.y - l.y*v0.x;
      sv1.x -= l.x*v1.x + l.y*v1.y; sv1.y -= l.x*v1.y - l.y*v1.x;
      sv2.x -= l.x*v2.x + l.y*v2.y; sv2.y -= l.x*v2.y - l.y*v2.x;
      sv3.x -= l.x*v3.x + l.y*v3.y; sv3.y -= l.x*v3.y - l.y*v3.x;
    }
  }
  s[JB][0] = sv0; s[JB][1] = sv1; s[JB][2] = sv2; s[JB][3] = sv3;
  float2* wp = vb + r*10 + (hf<<2);
  wp[0] = sv0; wp[1] = sv1; wp[2] = sv2; wp[3] = sv3;
}

#define DISPATCH8(FN, V) \
  switch (V){ \
    case 0: FN<0>(s, tb, vb, r, hf); break; \
    case 1: FN<1>(s, tb, vb, r, hf); break; \
    case 2: FN<2>(s, tb, vb, r, hf); break; \
    case 3: FN<3>(s, tb, vb, r, hf); break; \
    case 4: FN<4>(s, tb, vb, r, hf); break; \
    case 5: FN<5>(s, tb, vb, r, hf); break; \
    case 6: FN<6>(s, tb, vb, r, hf); break; \
    default: FN<7>(s, tb, vb, r, hf); break; }

__global__ __launch_bounds__(128) void kSolve(const float2* __restrict__ Lg, float2* __restrict__ X,
                                              const float* __restrict__ eb, int cf0){
  __shared__ float2 tb2[2][32*33];    // 16.9 KiB, double-buffered tile
  __shared__ float2 vbuf[2][32*10];   // 5.1 KiB, per-wave solved-block values
  __shared__ int seq[72];
  int fi = blockIdx.x;
  int f = cf0 + fi;
  const float2* Tf = Lg + (size_t)fi*TSTRIDE;
  float2* Xf = X + (size_t)f*CH*NB;
  int tid = threadIdx.x, wv = tid >> 6, lane = tid & 63, hf = lane >> 5, r = lane & 31;
  int cc = (blockIdx.y << 4) + (wv << 3) + (hf << 2);   // first of 4 cols
  if (tid == 0){
    int n = 0;
    for (int jb = 0; jb < 8; jb++){
      seq[n++] = jb | (jb << 4) | (1 << 12);
      for (int ib = jb+1; ib < 8; ib++) seq[n++] = ib | (jb << 4) | (0 << 12);
    }
    for (int jb = 7; jb >= 0; jb--){
      seq[n++] = jb | (jb << 4) | (2 << 12);
      for (int ii = jb-1; ii >= 0; ii--) seq[n++] = jb | (ii << 4) | (3 << 12);
    }
  }
  float2 s[8][4];
#pragma unroll
  for (int rb = 0; rb < 8; rb++){
    const float2* xp = Xf + (size_t)((rb << 5) + r)*NB + cc;
    float4 a = *(const float4*)xp, b = *(const float4*)(xp + 2);
    s[rb][0] = make_float2(a.x, a.y); s[rb][1] = make_float2(a.z, a.w);
    s[rb][2] = make_float2(b.x, b.y); s[rb][3] = make_float2(b.z, b.w);
  }
  // stage tile (0,0) into buffer 0: thread covers 8 complex
  {
    const float4* src = (const float4*)(Tf + (tid << 3));
    float4 a0 = src[0], a1 = src[1], a2 = src[2], a3 = src[3];
    int row = tid >> 2, col = (tid & 3) << 3;
    float2* d = &tb2[0][row*33 + col];
    d[0] = make_float2(a0.x, a0.y); d[1] = make_float2(a0.z, a0.w);
    d[2] = make_float2(a1.x, a1.y); d[3] = make_float2(a1.z, a1.w);
    d[4] = make_float2(a2.x, a2.y); d[5] = make_float2(a2.z, a2.w);
    d[6] = make_float2(a3.x, a3.y); d[7] = make_float2(a3.z, a3.w);
  }
  __syncthreads();
  float2* vb = vbuf[wv];
  int cur = 0;
#pragma unroll 1
  for (int t = 0; t < 72; t++){
    float4 p0, p1, p2, p3;
    bool pf = t < 71;
    if (pf){
      int e2 = seq[t+1];
      const float4* src = (const float4*)(Tf + ((size_t)tIdx(e2 & 15, (e2 >> 4) & 15) << 10) + (tid << 3));
      p0 = src[0]; p1 = src[1]; p2 = src[2]; p3 = src[3];
    }
    int e = seq[t];
    int type = e >> 12;
    const float2* tb = tb2[cur];
    if (type == 0){        int rbT = e & 15;        DISPATCH8(updF, rbT); }
    else if (type == 1){   int jb  = e & 15;        DISPATCH8(diagF, jb); }
    else if (type == 2){   int jb  = e & 15;        DISPATCH8(diagB, jb); }
    else {                 int rbT = (e >> 4) & 15; DISPATCH8(updB, rbT); }
    if (pf){
      int row = tid >> 2, col = (tid & 3) << 3;
      float2* d = &tb2[cur ^ 1][row*33 + col];
      d[0] = make_float2(p0.x, p0.y); d[1] = make_float2(p0.z, p0.w);
      d[2] = make_float2(p1.x, p1.y); d[3] = make_float2(p1.z, p1.w);
      d[4] = make_float2(p2.x, p2.y); d[5] = make_float2(p2.z, p2.w);
      d[6] = make_float2(p3.x, p3.y); d[7] = make_float2(p3.z, p3.w);
    }
    __syncthreads();
    cur ^= 1;
  }
  float te = 2.f * eb[f];
#pragma unroll
  for (int rb = 0; rb < 8; rb++){
    float2* xp = Xf + (size_t)((rb << 5) + r)*NB + cc;
    float4 a = *(const float4*)xp, b = *(const float4*)(xp + 2);
    *(float4*)xp       = make_float4(te*s[rb][0].x - a.x, te*s[rb][0].y - a.y,
                                     te*s[rb][1].x - a.z, te*s[rb][1].y - a.w);
    *(float4*)(xp + 2) = make_float4(te*s[rb][2].x - b.x, te*s[rb][2].y - b.y,
                                     te*s[rb][3].x - b.z, te*s[rb][3].y - b.w);
  }
}

// ---------------- inverse FFT stage 1: along ky (34 -> rows a=1..32) -------
__global__ __launch_bounds__(512) void kI1(const float2* __restrict__ X, float2* __restrict__ Y){
  __shared__ float pc[HW][NN], ps[HW][NN];
  int tid = threadIdx.x;
  for (int i = tid; i < HW*NN; i += 512){
    int a = i / NN, ky = i - a*NN;
    float s, c; sincosf(PI2*(float)(ky*(a+1))/34.f, &s, &c);
    pc[a][ky] = c; ps[a][ky] = s;
  }
  __syncthreads();
  int kx = blockIdx.x;
  int cc = (blockIdx.y << 3) + (tid >> 6);
  int b = tid & 63;
  float2 z[NN];
#pragma unroll
  for (int ky = 0; ky < NN; ky++) z[ky] = X[(((size_t)ky*NFH + kx)*CH + cc)*NB + b];
#pragma unroll 1
  for (int a = 0; a < HW; a++){
    float re = 0.f, im = 0.f;
#pragma unroll
    for (int ky = 0; ky < NN; ky++){
      float co = pc[a][ky], si = ps[a][ky];
      re += z[ky].x*co - z[ky].y*si;
      im += z[ky].x*si + z[ky].y*co;
    }
    Y[(((size_t)a*NFH + kx)*CH + cc)*NB + b] = make_float2(re, im);
  }
}

// ---------------- inverse FFT stage 2: along kx (18 -> real w=1..32) + bias
__global__ __launch_bounds__(256) void kI2(const float2* __restrict__ Y, const float* __restrict__ bias,
                                           float* __restrict__ out){
  __shared__ float tc[NFH][HW], tsn[NFH][HW];
  int tid = threadIdx.x;
  for (int i = tid; i < NFH*HW; i += 256){
    int kx = i >> 5, w = i & 31;
    float wt = (kx == 0 || kx == 17) ? (1.f/34.f) : (2.f/34.f);
    float s, c; sincosf(PI2*(float)(kx*(w+1))/34.f, &s, &c);
    tc[kx][w] = wt*c; tsn[kx][w] = wt*s;
  }
  __syncthreads();
  int cc = blockIdx.x;
  int a = (blockIdx.y << 2) + (tid >> 6);
  int b = tid & 63;
  float2 yv[NFH];
#pragma unroll
  for (int kx = 0; kx < NFH; kx++) yv[kx] = Y[(((size_t)a*NFH + kx)*CH + cc)*NB + b];
  float bi = bias[cc];
  float ov[HW];
#pragma unroll
  for (int w = 0; w < HW; w++){
    float acc = bi;
#pragma unroll
    for (int kx = 0; kx < NFH; kx++)
      acc += yv[kx].x*tc[kx][w] - yv[kx].y*tsn[kx][w];
    ov[w] = acc;
  }
  float4* op = (float4*)(out + (((size_t)b*CH + cc)*HW + a)*HW);
#pragma unroll
  for (int t = 0; t < 8; t++) op[t] = make_float4(ov[4*t], ov[4*t+1], ov[4*t+2], ov[4*t+3]);
}

extern "C" void kernel_launch(void* const* d_in, const int* in_sizes, int n_in,
                              void* d_out, int out_size, void* d_ws, size_t ws_size,
                              hipStream_t stream){
  (void)in_sizes; (void)n_in; (void)out_size;
  const float* x    = (const float*)d_in[0];
  const float* w    = (const float*)d_in[1];
  const float* bias = (const float*)d_in[2];
  float* out = (float*)d_out;
  char* ws = (char*)d_ws;

  const size_t X_BYTES  = (size_t)NFREQ*CH*NB*sizeof(float2);   // 80.2 MB
  const size_t WT_BYTES = (size_t)9*CH*CIN*sizeof(float);       // 2.35 MB
  const size_t C_BYTES  = (size_t)81*CH*CH*sizeof(float);       // 21.2 MB
  const size_t offX  = 0;
  const size_t offWT = offX + X_BYTES;
  const size_t offC  = offWT + WT_BYTES;
  const size_t offE  = offC + C_BYTES;
  const size_t offChunk = offE + 4096;
  const size_t perF = (size_t)TSTRIDE * sizeof(float2);          // 288 KB

  float2* X  = (float2*)(ws + offX);
  float*  wT = (float*)(ws + offWT);
  float*  C2 = (float*)(ws + offC);
  float*  eb = (float*)(ws + offE);
  float2* U  = (float2*)(ws + offChunk);
  float2* Mb = (float2*)(ws + offChunk);
  float2* Y  = (float2*)(ws + offChunk);

  size_t avail = ws_size > offChunk ? ws_size - offChunk : 0;
  int F = (int)(avail / perF);
  if (F < 1) F = 1;
  if (F > NFREQ) F = NFREQ;
  int nch = (NFREQ + F - 1) / F;
  F = (NFREQ + nch - 1) / nch;

  kF1<<<dim3(CH, 8), 256, 0, stream>>>(x, U);
  kF2<<<dim3(NFH, 32), 512, 0, stream>>>(U, X);
  kT0<<<(9*CH*CIN + 255)/256, 256, 0, stream>>>(w, wT);
  kC<<<dim3(81, 16), 256, 0, stream>>>(wT, C2);

  for (int cf0 = 0; cf0 < NFREQ; cf0 += F){
    int cF = (NFREQ - cf0 < F) ? (NFREQ - cf0) : F;
    kM<<<dim3(36, 32, (cF + 63) >> 6), 64, 0, stream>>>(C2, Mb, cf0, cF);
    kEps<<<cF, 256, 0, stream>>>(Mb, eb, cf0);
    for (int pb = 0; pb < 8; pb++){
      kPanel<<<cF, 256, 0, stream>>>(Mb, pb);
      int nrem = 7 - pb;
      int npairs = (nrem*(nrem+1)) >> 1;
      if (npairs > 0)
        kSyrk<<<dim3(cF, npairs), 256, 0, stream>>>(Mb, pb);
    }
    kSolve<<<dim3(cF, 4), 128, 0, stream>>>(Mb, X, eb, cf0);
  }

  kI1<<<dim3(NFH, 32), 512, 0, stream>>>(X, Y);
  kI2<<<dim3(CH, 8), 256, 0, stream>>>(Y, bias, out);
}